// Round 2
// baseline (498.920 us; speedup 1.0000x reference)
//
#include <hip/hip_runtime.h>

typedef short short8 __attribute__((ext_vector_type(8)));
typedef float f32x4 __attribute__((ext_vector_type(4)));
typedef unsigned short u16x4 __attribute__((ext_vector_type(4)));

constexpr int NB = 16, CIN = 128, LIN = 2048, CO = 256;
constexpr int SL = 2041;                 // output sequence length
constexpr int MT = NB * SL;              // 32656 valid rows
constexpr int MP = 32768;                // padded rows
constexpr int XTS = 136;                 // xT row stride (elems): 16B-aligned, 4-bank shift/row

// ---- workspace layout (bytes, all 256-aligned) ----
constexpr size_t XT_OFF = 0;
constexpr size_t XT_SZ  = (size_t)NB*LIN*XTS*2 + 65536;  // bf16 xT [n][s][136] + OOB slack
constexpr size_t CW_OFF = XT_OFF + XT_SZ;
constexpr size_t CW_SZ  = (size_t)CO*CIN*8*2;            // conv_w bf16 [256][1024], kk=kp*128+ci
constexpr size_t WQ_OFF = CW_OFF + CW_SZ;
constexpr size_t WB_SZ  = (size_t)CO*CO*2;
constexpr size_t WK_OFF = WQ_OFF + WB_SZ;
constexpr size_t WV_OFF = WK_OFF + WB_SZ;
constexpr size_t H_OFF  = WV_OFF + WB_SZ;
constexpr size_t HB_SZ  = (size_t)MP*CO*2;               // 16 MB each
constexpr size_t Q_OFF  = H_OFF + HB_SZ;
constexpr size_t K_OFF  = Q_OFF + HB_SZ;
constexpr size_t VT_OFF = K_OFF + HB_SZ;                 // v transposed [256][16][2048]

__device__ inline unsigned short f2bf(float f) {
  union { float f; unsigned int u; } v; v.f = f;
  unsigned int r = v.u + 0x7fffu + ((v.u >> 16) & 1u);
  return (unsigned short)(r >> 16);
}

#if defined(__has_builtin)
#if __has_builtin(__builtin_amdgcn_global_load_lds)
#define HAVE_GLDS 1
#endif
#endif

__device__ inline void gld16(const unsigned short* g, void* l) {
#ifdef HAVE_GLDS
  __builtin_amdgcn_global_load_lds(
      (const __attribute__((address_space(1))) void*)g,
      (__attribute__((address_space(3))) void*)l, 16, 0, 0);
#else
  *(short8*)l = *(const short8*)g;
#endif
}

// ---------------- zero d_out (it is poisoned 0xAA before every launch) ----------------
__global__ void zero_kernel(float* __restrict__ p, int count) {
  int i = (blockIdx.x * 256 + threadIdx.x) * 4;
  if (i < count) *(float4*)(p + i) = make_float4(0.f, 0.f, 0.f, 0.f);
}

// ---------------- x transpose + bf16: [16][128][2048] f32 -> [16][2048][136] bf16 ----------------
// grid (64 s-tiles, 4 c-tiles, 16 n), block (32,8)
__global__ void xpose_kernel(const float* __restrict__ x, unsigned short* __restrict__ xt) {
  __shared__ float tile[32][33];
  const int tx = threadIdx.x, ty = threadIdx.y;
  const int s0 = blockIdx.x * 32, c0 = blockIdx.y * 32, n = blockIdx.z;
  #pragma unroll
  for (int r = 0; r < 4; ++r)
    tile[ty * 4 + r][tx] = x[((size_t)(n * CIN + c0 + ty * 4 + r)) * LIN + s0 + tx];
  __syncthreads();
  #pragma unroll
  for (int r = 0; r < 4; ++r)
    xt[((size_t)(n * LIN + s0 + ty * 4 + r)) * XTS + c0 + tx] = f2bf(tile[tx][ty * 4 + r]);
}

// ---------------- conv weight reorder: [256][128][8] f32 -> bf16 [co][kp*128+ci] ----------------
__global__ void wconv_kernel(const float* __restrict__ w, unsigned short* __restrict__ o) {
  int idx = blockIdx.x * 256 + threadIdx.x;      // 0..262143
  int co = idx >> 10, r = idx & 1023, kp = r >> 7, ci = r & 127;
  o[idx] = f2bf(w[co * 1024 + ci * 8 + kp]);
}

// ---------------- q/k/v weight cvt (3 arrays, one launch) ----------------
__global__ void wqkv_kernel(const float* __restrict__ a, const float* __restrict__ b,
                            const float* __restrict__ c, unsigned short* __restrict__ oa,
                            unsigned short* __restrict__ ob, unsigned short* __restrict__ oc) {
  int z = blockIdx.x >> 6, lb = blockIdx.x & 63;
  const float* src = (z == 0) ? a : (z == 1) ? b : c;
  unsigned short* dst = (z == 0) ? oa : (z == 1) ? ob : oc;
  int i = (lb * 256 + threadIdx.x) * 4;
  float4 v = *(const float4*)(src + i);
  u16x4 r;
  r.x = f2bf(v.x); r.y = f2bf(v.y); r.z = f2bf(v.z); r.w = f2bf(v.w);
  *(u16x4*)(dst + i) = r;
}

// ---------------- conv as implicit GEMM (transposed-x, aligned b128 frags) ----------------
// grid (16 s-tiles, 16 n, 2 d-tiles), 256 threads
__global__ __launch_bounds__(256) void conv_gemm(
    const unsigned short* __restrict__ xt,   // [16][2048][136] bf16
    const unsigned short* __restrict__ wb,   // [256][1024] bf16 (kk = kp*128+ci)
    const float* __restrict__ bias,          // [256]
    unsigned short* __restrict__ h)          // [MP][256] bf16
{
  __shared__ unsigned short sX[18432];       // 36 KB window [135 s][136 ci]
  __shared__ unsigned short sB[4096];        // 8 KB weight chunk [128 co][32 kk] (chunk-swizzled)
  const int tid = threadIdx.x;
  const int w = tid >> 6, lane = tid & 63, quad = lane >> 4, l16 = lane & 15;
  const int n  = blockIdx.y;
  const int s0 = blockIdx.x * 128;
  const int d0 = blockIdx.z * 128;

  { // stage contiguous x window once: 2304 x 16 B
    const unsigned short* xbase = xt + ((size_t)n * LIN + s0) * XTS;
    #pragma unroll
    for (int i = 0; i < 9; ++i) {
      int u = i * 256 + tid;
      gld16(xbase + u * 8, ((char*)sX) + u * 16);
    }
  }

  f32x4 acc[2][8];
  #pragma unroll
  for (int i = 0; i < 2; ++i)
    #pragma unroll
    for (int j = 0; j < 8; ++j) acc[i][j] = (f32x4){0.f, 0.f, 0.f, 0.f};

  for (int kc = 0; kc < 32; ++kc) {
    const int kp = kc >> 2, ci0 = (kc & 3) * 32;
    __syncthreads();   // protect sB readers of previous chunk; completes X stage on kc=0
    #pragma unroll
    for (int i2 = 0; i2 < 2; ++i2) {
      int off = (i2 * 256 + tid) * 16;       // byte offset in sB
      int row = off >> 6, kgs = (off >> 4) & 3;
      int kg = kgs ^ ((row >> 1) & 3);       // swizzle: slot kgs holds global chunk kg
      gld16(wb + (size_t)(d0 + row) * 1024 + kp * 128 + ci0 + kg * 8, ((char*)sB) + off);
    }
    __syncthreads();

    short8 bfr[8];
    #pragma unroll
    for (int j = 0; j < 8; ++j) {
      int r = j * 16 + l16;
      bfr[j] = *(const short8*)(sB + r * 32 + (quad ^ ((r >> 1) & 3)) * 8);
    }

    #pragma unroll
    for (int i = 0; i < 2; ++i) {
      int srow = w * 32 + i * 16 + l16;
      short8 afr = *(const short8*)(sX + (srow + kp) * XTS + ci0 + quad * 8);
      #pragma unroll
      for (int j = 0; j < 8; ++j)
        acc[i][j] = __builtin_amdgcn_mfma_f32_16x16x32_bf16(afr, bfr[j], acc[i][j], 0, 0, 0);
    }
  }

  #pragma unroll
  for (int i = 0; i < 2; ++i)
    #pragma unroll
    for (int j = 0; j < 8; ++j) {
      int col = d0 + j * 16 + l16;
      float bv = bias[col];
      #pragma unroll
      for (int jj = 0; jj < 4; ++jj) {
        int s = s0 + w * 32 + i * 16 + quad * 4 + jj;
        if (s < SL) {
          float val = fmaxf(acc[i][j][jj] + bv, 0.f);
          h[(size_t)(n * SL + s) * CO + col] = f2bf(val);
        }
      }
    }
}

// ---------------- q/k/v linear GEMMs ----------------
// grid (256 m-tiles, 2 d-tiles, 3 {q,k,v}), 256 threads
__global__ __launch_bounds__(256) void lin_gemm(
    const unsigned short* __restrict__ A,    // h [MP][256]
    const unsigned short* __restrict__ Bq, const unsigned short* __restrict__ Bk,
    const unsigned short* __restrict__ Bv,
    const float* __restrict__ biq, const float* __restrict__ bik,
    const float* __restrict__ biv,
    unsigned short* __restrict__ qb, unsigned short* __restrict__ kb,
    unsigned short* __restrict__ vtb)
{
  __shared__ unsigned short sA[4096];
  __shared__ unsigned short sB[4096];
  const int tid = threadIdx.x;
  const int w = tid >> 6, lane = tid & 63, quad = lane >> 4, l16 = lane & 15;
  const int m0 = blockIdx.x * 128, d0 = blockIdx.y * 128, z = blockIdx.z;
  const unsigned short* B = (z == 0) ? Bq : (z == 1) ? Bk : Bv;
  const float* bias        = (z == 0) ? biq : (z == 1) ? bik : biv;

  f32x4 acc[2][8];
  #pragma unroll
  for (int i = 0; i < 2; ++i)
    #pragma unroll
    for (int j = 0; j < 8; ++j) acc[i][j] = (f32x4){0.f, 0.f, 0.f, 0.f};

  for (int kc = 0; kc < 8; ++kc) {
    __syncthreads();
    #pragma unroll
    for (int i2 = 0; i2 < 2; ++i2) {
      int off = (i2 * 256 + tid) * 16;
      int row = off >> 6, kgs = (off >> 4) & 3;
      int kg = kgs ^ ((row >> 1) & 3);
      gld16(A + (size_t)(m0 + row) * CO + kc * 32 + kg * 8, ((char*)sA) + off);
      gld16(B + (size_t)(d0 + row) * CO + kc * 32 + kg * 8, ((char*)sB) + off);
    }
    __syncthreads();

    short8 afr[2], bfr[8];
    #pragma unroll
    for (int i = 0; i < 2; ++i) {
      int r = w * 32 + i * 16 + l16;
      afr[i] = *(const short8*)(sA + r * 32 + (quad ^ ((r >> 1) & 3)) * 8);
    }
    #pragma unroll
    for (int j = 0; j < 8; ++j) {
      int r = j * 16 + l16;
      bfr[j] = *(const short8*)(sB + r * 32 + (quad ^ ((r >> 1) & 3)) * 8);
    }
    #pragma unroll
    for (int i = 0; i < 2; ++i)
      #pragma unroll
      for (int j = 0; j < 8; ++j)
        acc[i][j] = __builtin_amdgcn_mfma_f32_16x16x32_bf16(afr[i], bfr[j], acc[i][j], 0, 0, 0);
  }

  #pragma unroll
  for (int i = 0; i < 2; ++i)
    #pragma unroll
    for (int j = 0; j < 8; ++j) {
      int col = d0 + j * 16 + l16;
      float bv = bias[col];
      #pragma unroll
      for (int jj = 0; jj < 4; ++jj) {
        int m = m0 + w * 32 + i * 16 + quad * 4 + jj;
        float val = acc[i][j][jj] + bv;
        if (z < 2) {
          ((z == 0) ? qb : kb)[(size_t)m * CO + col] = f2bf(val);
        } else if (m < MT) {
          int nn = m / SL, ss = m - nn * SL;
          vtb[(size_t)col * MP + nn * 2048 + ss] = f2bf(val);  // transposed, per-n padded
        }
      }
    }
}

// ---------------- fused sigmoid attention, split-t, atomic accumulate ----------------
// grid (32 s-tiles of 64, 16 n, 2 t-halves), 256 threads; LDS exactly 40 KB -> 4 blocks/CU
__global__ __launch_bounds__(256) void attn_kernel(
    const unsigned short* __restrict__ qb,   // [MP][256]
    const unsigned short* __restrict__ kb,   // [MP][256]
    const unsigned short* __restrict__ vtb,  // [256][16][2048]
    float* __restrict__ out)                 // [16][256][2041], pre-zeroed
{
  __shared__ char smem[40960];
  unsigned short* sKV = (unsigned short*)smem;            // 32 KB
  unsigned short* sP  = (unsigned short*)(smem + 32768);  // 8 KB [64 s][64 t] chunk-swizzled
  const int tid = threadIdx.x;
  const int w = tid >> 6, lane = tid & 63, quad = lane >> 4, l16 = lane & 15;
  const int n = blockIdx.y, s0 = blockIdx.x * 64, z = blockIdx.z;
  const int srow = w * 16 + l16;

  // Q fragments in registers for the whole t-loop
  short8 qf[8];
  {
    const unsigned short* qp = qb + (size_t)(n * SL + s0 + srow) * CO + quad * 8;
    #pragma unroll
    for (int c = 0; c < 8; ++c) qf[c] = *(const short8*)(qp + c * 32);
  }

  f32x4 o[16];
  #pragma unroll
  for (int jd = 0; jd < 16; ++jd) o[jd] = (f32x4){0.f, 0.f, 0.f, 0.f};

  for (int tt = 0; tt < 16; ++tt) {
    const int t0 = z * 1024 + tt * 64;
    __syncthreads();   // prev iter PV readers done with sKV
    #pragma unroll
    for (int i = 0; i < 8; ++i) {          // stage K tile [8 c][64 t][32], chunk-swizzled
      int u = (i * 256 + tid) * 8;
      int c = u >> 11, rem = u & 2047, trow = rem >> 5, kgs = (rem >> 3) & 3;
      int kg = kgs ^ ((trow >> 1) & 3);
      gld16(kb + (size_t)(n * SL + t0 + trow) * CO + c * 32 + kg * 8,
            ((char*)sKV) + u * 2);
    }
    __syncthreads();

    f32x4 sa[4];
    #pragma unroll
    for (int j = 0; j < 4; ++j) sa[j] = (f32x4){0.f, 0.f, 0.f, 0.f};
    #pragma unroll
    for (int c = 0; c < 8; ++c)
      #pragma unroll
      for (int j = 0; j < 4; ++j) {
        int r = j * 16 + l16;
        short8 bfr = *(const short8*)(sKV + c * 2048 + r * 32 + (quad ^ ((r >> 1) & 3)) * 8);
        sa[j] = __builtin_amdgcn_mfma_f32_16x16x32_bf16(qf[c], bfr, sa[j], 0, 0, 0);
      }

    // sigmoid(x/16), mask invalid t, C-layout -> A-layout via swizzled sP
    #pragma unroll
    for (int j = 0; j < 4; ++j)
      #pragma unroll
      for (int jj = 0; jj < 4; ++jj) {
        int t  = j * 16 + l16;             // t within tile
        int sp = w * 16 + quad * 4 + jj;   // s within tile
        float p = 1.f / (1.f + __expf(-sa[j][jj] * 0.0625f));
        sP[sp * 64 + (((t >> 3) ^ (sp & 7)) << 3) + (t & 7)] =
            (t0 + t < SL) ? f2bf(p) : (unsigned short)0;
      }
    __syncthreads();   // sP ready AND all waves done reading K

    #pragma unroll
    for (int i = 0; i < 8; ++i) {          // stage V tile [2 tc][256 d][32], chunk-swizzled
      int u = (i * 256 + tid) * 8;
      int tc = u >> 13, rem = u & 8191, drow = rem >> 5, kgs = (rem >> 3) & 3;
      int kg = kgs ^ ((drow >> 1) & 3);
      gld16(vtb + (size_t)drow * MP + n * 2048 + t0 + tc * 32 + kg * 8,
            ((char*)sKV) + u * 2);
    }
    __syncthreads();

    #pragma unroll
    for (int tc = 0; tc < 2; ++tc) {
      int ctq = tc * 4 + quad;
      short8 pa = *(const short8*)(sP + srow * 64 + ((ctq ^ (srow & 7)) << 3));
      #pragma unroll
      for (int jd = 0; jd < 16; ++jd) {
        int r = jd * 16 + l16;
        short8 bv = *(const short8*)(sKV + tc * 8192 + r * 32 + (quad ^ ((r >> 1) & 3)) * 8);
        o[jd] = __builtin_amdgcn_mfma_f32_16x16x32_bf16(pa, bv, o[jd], 0, 0, 0);
      }
    }
  }

  // epilogue: transpose o through LDS (stride 68 -> aligned float4, ~2-way banks),
  // then coalesced atomicAdd runs into out[n][d][s]
  float* sOut = (float*)smem;   // 128 x 68 fp32 = 34816 B
  #pragma unroll
  for (int h = 0; h < 2; ++h) {
    __syncthreads();
    #pragma unroll
    for (int jd8 = 0; jd8 < 8; ++jd8) {
      int drel = jd8 * 16 + l16;
      #pragma unroll
      for (int jj = 0; jj < 4; ++jj)
        sOut[drel * 68 + w * 16 + quad * 4 + jj] = o[h * 8 + jd8][jj];
    }
    __syncthreads();
    #pragma unroll
    for (int r8 = 0; r8 < 8; ++r8) {
      int drel = r8 * 16 + (tid >> 4);
      int sc = (tid & 15) * 4;
      float4 v = *(float4*)(sOut + drel * 68 + sc);
      int s = s0 + sc;
      float* op = out + (size_t)n * CO * SL + (size_t)(h * 128 + drel) * SL + s;
      if (s + 3 < SL) {
        atomicAdd(op, v.x); atomicAdd(op + 1, v.y);
        atomicAdd(op + 2, v.z); atomicAdd(op + 3, v.w);
      } else {
        if (s < SL)     atomicAdd(op, v.x);
        if (s + 1 < SL) atomicAdd(op + 1, v.y);
        if (s + 2 < SL) atomicAdd(op + 2, v.z);
        if (s + 3 < SL) atomicAdd(op + 3, v.w);
      }
    }
  }
}

extern "C" void kernel_launch(void* const* d_in, const int* in_sizes, int n_in,
                              void* d_out, int out_size, void* d_ws, size_t ws_size,
                              hipStream_t stream) {
  const float* x      = (const float*)d_in[0];
  const float* conv_w = (const float*)d_in[1];
  const float* conv_b = (const float*)d_in[2];
  const float* wq     = (const float*)d_in[3];
  const float* bq     = (const float*)d_in[4];
  const float* wk     = (const float*)d_in[5];
  const float* bk     = (const float*)d_in[6];
  const float* wv     = (const float*)d_in[7];
  const float* bv     = (const float*)d_in[8];

  char* ws = (char*)d_ws;
  unsigned short* xt  = (unsigned short*)(ws + XT_OFF);
  unsigned short* cw  = (unsigned short*)(ws + CW_OFF);
  unsigned short* wqb = (unsigned short*)(ws + WQ_OFF);
  unsigned short* wkb = (unsigned short*)(ws + WK_OFF);
  unsigned short* wvb = (unsigned short*)(ws + WV_OFF);
  unsigned short* hb  = (unsigned short*)(ws + H_OFF);
  unsigned short* qb  = (unsigned short*)(ws + Q_OFF);
  unsigned short* kb  = (unsigned short*)(ws + K_OFF);
  unsigned short* vtb = (unsigned short*)(ws + VT_OFF);

  hipLaunchKernelGGL(zero_kernel,  dim3(8160), dim3(256), 0, stream, (float*)d_out, out_size);
  hipLaunchKernelGGL(xpose_kernel, dim3(64, 4, 16), dim3(32, 8), 0, stream, x, xt);
  hipLaunchKernelGGL(wconv_kernel, dim3(1024), dim3(256), 0, stream, conv_w, cw);
  hipLaunchKernelGGL(wqkv_kernel,  dim3(192), dim3(256), 0, stream,
                     wq, wk, wv, wqb, wkb, wvb);
  hipLaunchKernelGGL(conv_gemm, dim3(16, 16, 2), dim3(256), 0, stream, xt, cw, conv_b, hb);
  hipLaunchKernelGGL(lin_gemm,  dim3(256, 2, 3), dim3(256), 0, stream,
                     hb, wqb, wkb, wvb, bq, bk, bv, qb, kb, vtb);
  hipLaunchKernelGGL(attn_kernel, dim3(32, 16, 2), dim3(256), 0, stream,
                     qb, kb, vtb, (float*)d_out);
}

// Round 3
// 286.944 us; speedup vs baseline: 1.7387x; 1.7387x over previous
//
#include <hip/hip_runtime.h>

typedef short short8 __attribute__((ext_vector_type(8)));
typedef float f32x4 __attribute__((ext_vector_type(4)));
typedef float f32x16 __attribute__((ext_vector_type(16)));
typedef unsigned short u16x4 __attribute__((ext_vector_type(4)));

constexpr int NB = 16, CIN = 128, LIN = 2048, CO = 256;
constexpr int SL = 2041;                 // output sequence length
constexpr int MT = NB * SL;              // 32656 valid rows
constexpr int MP = 32768;                // padded rows
constexpr int XTS = 136;                 // xT row stride (elems): 16B-aligned, 4-bank shift/row

// ---- workspace layout (bytes, all 256-aligned) ----
constexpr size_t XT_OFF = 0;
constexpr size_t XT_SZ  = (size_t)NB*LIN*XTS*2 + 65536;  // bf16 xT [n][s][136] + OOB slack
constexpr size_t CW_OFF = XT_OFF + XT_SZ;
constexpr size_t CW_SZ  = (size_t)CO*CIN*8*2;            // conv_w bf16 [256][1024], kk=kp*128+ci
constexpr size_t WQ_OFF = CW_OFF + CW_SZ;
constexpr size_t WB_SZ  = (size_t)CO*CO*2;
constexpr size_t WK_OFF = WQ_OFF + WB_SZ;
constexpr size_t WV_OFF = WK_OFF + WB_SZ;
constexpr size_t H_OFF  = WV_OFF + WB_SZ;
constexpr size_t HB_SZ  = (size_t)MP*CO*2;               // 16 MB each
constexpr size_t Q_OFF  = H_OFF + HB_SZ;
constexpr size_t K_OFF  = Q_OFF + HB_SZ;
constexpr size_t VT_OFF = K_OFF + HB_SZ;                 // v transposed [256][16][2048]

__device__ inline unsigned short f2bf(float f) {
  union { float f; unsigned int u; } v; v.f = f;
  unsigned int r = v.u + 0x7fffu + ((v.u >> 16) & 1u);
  return (unsigned short)(r >> 16);
}

#if defined(__has_builtin)
#if __has_builtin(__builtin_amdgcn_global_load_lds)
#define HAVE_GLDS 1
#endif
#endif

__device__ inline void gld16(const unsigned short* g, void* l) {
#ifdef HAVE_GLDS
  __builtin_amdgcn_global_load_lds(
      (const __attribute__((address_space(1))) void*)g,
      (__attribute__((address_space(3))) void*)l, 16, 0, 0);
#else
  *(short8*)l = *(const short8*)g;
#endif
}

// ---------------- x transpose + bf16: [16][128][2048] f32 -> [16][2048][136] bf16 ----------------
// grid (64 s-tiles, 4 c-tiles, 16 n), block (32,8)
__global__ void xpose_kernel(const float* __restrict__ x, unsigned short* __restrict__ xt) {
  __shared__ float tile[32][33];
  const int tx = threadIdx.x, ty = threadIdx.y;
  const int s0 = blockIdx.x * 32, c0 = blockIdx.y * 32, n = blockIdx.z;
  #pragma unroll
  for (int r = 0; r < 4; ++r)
    tile[ty * 4 + r][tx] = x[((size_t)(n * CIN + c0 + ty * 4 + r)) * LIN + s0 + tx];
  __syncthreads();
  #pragma unroll
  for (int r = 0; r < 4; ++r)
    xt[((size_t)(n * LIN + s0 + ty * 4 + r)) * XTS + c0 + tx] = f2bf(tile[tx][ty * 4 + r]);
}

// ---------------- conv weight reorder: [256][128][8] f32 -> bf16 [co][kp*128+ci] ----------------
__global__ void wconv_kernel(const float* __restrict__ w, unsigned short* __restrict__ o) {
  int idx = blockIdx.x * 256 + threadIdx.x;      // 0..262143
  int co = idx >> 10, r = idx & 1023, kp = r >> 7, ci = r & 127;
  o[idx] = f2bf(w[co * 1024 + ci * 8 + kp]);
}

// ---------------- q/k/v weight cvt (3 arrays, one launch) ----------------
__global__ void wqkv_kernel(const float* __restrict__ a, const float* __restrict__ b,
                            const float* __restrict__ c, unsigned short* __restrict__ oa,
                            unsigned short* __restrict__ ob, unsigned short* __restrict__ oc) {
  int z = blockIdx.x >> 6, lb = blockIdx.x & 63;
  const float* src = (z == 0) ? a : (z == 1) ? b : c;
  unsigned short* dst = (z == 0) ? oa : (z == 1) ? ob : oc;
  int i = (lb * 256 + threadIdx.x) * 4;
  float4 v = *(const float4*)(src + i);
  u16x4 r;
  r.x = f2bf(v.x); r.y = f2bf(v.y); r.z = f2bf(v.z); r.w = f2bf(v.w);
  *(u16x4*)(dst + i) = r;
}

// ---------------- conv as implicit GEMM (transposed-x, aligned b128 frags) ----------------
// grid (16 s-tiles, 16 n, 2 d-tiles), 256 threads
__global__ __launch_bounds__(256) void conv_gemm(
    const unsigned short* __restrict__ xt,   // [16][2048][136] bf16
    const unsigned short* __restrict__ wb,   // [256][1024] bf16 (kk = kp*128+ci)
    const float* __restrict__ bias,          // [256]
    unsigned short* __restrict__ h)          // [MP][256] bf16
{
  __shared__ unsigned short sX[18432];       // 36 KB window [135 s][136 ci]
  __shared__ unsigned short sB[4096];        // 8 KB weight chunk [128 co][32 kk] (chunk-swizzled)
  const int tid = threadIdx.x;
  const int w = tid >> 6, lane = tid & 63, quad = lane >> 4, l16 = lane & 15;
  const int n  = blockIdx.y;
  const int s0 = blockIdx.x * 128;
  const int d0 = blockIdx.z * 128;

  { // stage contiguous x window once: 2304 x 16 B
    const unsigned short* xbase = xt + ((size_t)n * LIN + s0) * XTS;
    #pragma unroll
    for (int i = 0; i < 9; ++i) {
      int u = i * 256 + tid;
      gld16(xbase + u * 8, ((char*)sX) + u * 16);
    }
  }

  f32x4 acc[2][8];
  #pragma unroll
  for (int i = 0; i < 2; ++i)
    #pragma unroll
    for (int j = 0; j < 8; ++j) acc[i][j] = (f32x4){0.f, 0.f, 0.f, 0.f};

  for (int kc = 0; kc < 32; ++kc) {
    const int kp = kc >> 2, ci0 = (kc & 3) * 32;
    __syncthreads();   // protect sB readers of previous chunk; completes X stage on kc=0
    #pragma unroll
    for (int i2 = 0; i2 < 2; ++i2) {
      int off = (i2 * 256 + tid) * 16;       // byte offset in sB
      int row = off >> 6, kgs = (off >> 4) & 3;
      int kg = kgs ^ ((row >> 1) & 3);       // swizzle: slot kgs holds global chunk kg
      gld16(wb + (size_t)(d0 + row) * 1024 + kp * 128 + ci0 + kg * 8, ((char*)sB) + off);
    }
    __syncthreads();

    short8 bfr[8];
    #pragma unroll
    for (int j = 0; j < 8; ++j) {
      int r = j * 16 + l16;
      bfr[j] = *(const short8*)(sB + r * 32 + (quad ^ ((r >> 1) & 3)) * 8);
    }

    #pragma unroll
    for (int i = 0; i < 2; ++i) {
      int srow = w * 32 + i * 16 + l16;
      short8 afr = *(const short8*)(sX + (srow + kp) * XTS + ci0 + quad * 8);
      #pragma unroll
      for (int j = 0; j < 8; ++j)
        acc[i][j] = __builtin_amdgcn_mfma_f32_16x16x32_bf16(afr, bfr[j], acc[i][j], 0, 0, 0);
    }
  }

  #pragma unroll
  for (int i = 0; i < 2; ++i)
    #pragma unroll
    for (int j = 0; j < 8; ++j) {
      int col = d0 + j * 16 + l16;
      float bv = bias[col];
      #pragma unroll
      for (int jj = 0; jj < 4; ++jj) {
        int s = s0 + w * 32 + i * 16 + quad * 4 + jj;
        if (s < SL) {
          float val = fmaxf(acc[i][j][jj] + bv, 0.f);
          h[(size_t)(n * SL + s) * CO + col] = f2bf(val);
        }
      }
    }
}

// ---------------- q/k/v linear GEMMs ----------------
// grid (256 m-tiles, 2 d-tiles, 3 {q,k,v}), 256 threads
__global__ __launch_bounds__(256) void lin_gemm(
    const unsigned short* __restrict__ A,    // h [MP][256]
    const unsigned short* __restrict__ Bq, const unsigned short* __restrict__ Bk,
    const unsigned short* __restrict__ Bv,
    const float* __restrict__ biq, const float* __restrict__ bik,
    const float* __restrict__ biv,
    unsigned short* __restrict__ qb, unsigned short* __restrict__ kb,
    unsigned short* __restrict__ vtb)
{
  __shared__ unsigned short sA[4096];
  __shared__ unsigned short sB[4096];
  const int tid = threadIdx.x;
  const int w = tid >> 6, lane = tid & 63, quad = lane >> 4, l16 = lane & 15;
  const int m0 = blockIdx.x * 128, d0 = blockIdx.y * 128, z = blockIdx.z;
  const unsigned short* B = (z == 0) ? Bq : (z == 1) ? Bk : Bv;
  const float* bias        = (z == 0) ? biq : (z == 1) ? bik : biv;

  f32x4 acc[2][8];
  #pragma unroll
  for (int i = 0; i < 2; ++i)
    #pragma unroll
    for (int j = 0; j < 8; ++j) acc[i][j] = (f32x4){0.f, 0.f, 0.f, 0.f};

  for (int kc = 0; kc < 8; ++kc) {
    __syncthreads();
    #pragma unroll
    for (int i2 = 0; i2 < 2; ++i2) {
      int off = (i2 * 256 + tid) * 16;
      int row = off >> 6, kgs = (off >> 4) & 3;
      int kg = kgs ^ ((row >> 1) & 3);
      gld16(A + (size_t)(m0 + row) * CO + kc * 32 + kg * 8, ((char*)sA) + off);
      gld16(B + (size_t)(d0 + row) * CO + kc * 32 + kg * 8, ((char*)sB) + off);
    }
    __syncthreads();

    short8 afr[2], bfr[8];
    #pragma unroll
    for (int i = 0; i < 2; ++i) {
      int r = w * 32 + i * 16 + l16;
      afr[i] = *(const short8*)(sA + r * 32 + (quad ^ ((r >> 1) & 3)) * 8);
    }
    #pragma unroll
    for (int j = 0; j < 8; ++j) {
      int r = j * 16 + l16;
      bfr[j] = *(const short8*)(sB + r * 32 + (quad ^ ((r >> 1) & 3)) * 8);
    }
    #pragma unroll
    for (int i = 0; i < 2; ++i)
      #pragma unroll
      for (int j = 0; j < 8; ++j)
        acc[i][j] = __builtin_amdgcn_mfma_f32_16x16x32_bf16(afr[i], bfr[j], acc[i][j], 0, 0, 0);
  }

  #pragma unroll
  for (int i = 0; i < 2; ++i)
    #pragma unroll
    for (int j = 0; j < 8; ++j) {
      int col = d0 + j * 16 + l16;
      float bv = bias[col];
      #pragma unroll
      for (int jj = 0; jj < 4; ++jj) {
        int m = m0 + w * 32 + i * 16 + quad * 4 + jj;
        float val = acc[i][j][jj] + bv;
        if (z < 2) {
          ((z == 0) ? qb : kb)[(size_t)m * CO + col] = f2bf(val);
        } else if (m < MT) {
          int nn = m / SL, ss = m - nn * SL;
          vtb[(size_t)col * MP + nn * 2048 + ss] = f2bf(val);  // transposed, per-n padded
        }
      }
    }
}

// ---------------- fused sigmoid attention, 32x32x16 MFMA ----------------
// grid (32 s-tiles of 64, 16 n), 256 threads = 4 waves.
// Wave w: mi = w&1 (s-half), wh = w>>1 (t-half for QK, d-half for PV).
__global__ __launch_bounds__(256) void attn_kernel(
    const unsigned short* __restrict__ qb,   // [MP][256]
    const unsigned short* __restrict__ kb,   // [MP][256]
    const unsigned short* __restrict__ vtb,  // [256][16][2048]
    float* __restrict__ out)                 // [16][256][2041]
{
  __shared__ char smem[40960];
  unsigned short* sKV = (unsigned short*)smem;            // 32 KB: K [64t][256c] / V [256d][64t]
  unsigned short* sP  = (unsigned short*)(smem + 32768);  // 8 KB: P [64s][64t] chunk-swizzled
  const int tid = threadIdx.x;
  const int w = tid >> 6, lane = tid & 63;
  const int half = lane >> 5, l32 = lane & 31;
  const int n = blockIdx.y, s0 = blockIdx.x * 64;
  const int mi = w & 1, wh = w >> 1;

  // Q A-frags in registers: A[m=l32][k = kk*16 + half*8 + j]
  short8 qf[16];
  {
    const unsigned short* qp =
        qb + (size_t)(n * SL + s0 + mi * 32 + l32) * CO + half * 8;
    #pragma unroll
    for (int kk = 0; kk < 16; ++kk) qf[kk] = *(const short8*)(qp + kk * 16);
  }

  f32x16 o[4];
  #pragma unroll
  for (int di = 0; di < 4; ++di)
    #pragma unroll
    for (int r = 0; r < 16; ++r) o[di][r] = 0.f;

  for (int t0 = 0; t0 < 2048; t0 += 64) {
    __syncthreads();   // prev-iter V/P readers done with sKV/sP
    // stage K tile [64 t][256 c]: 32 chunks/row, slot s holds global chunk s^(t&31)
    #pragma unroll
    for (int i = 0; i < 8; ++i) {
      int u = i * 256 + tid;
      int trow = u >> 5, slot = u & 31;
      gld16(kb + (size_t)(n * SL + t0 + trow) * CO + (slot ^ (trow & 31)) * 8,
            ((char*)sKV) + u * 16);
    }
    __syncthreads();

    // QK^T: one 32x32 C-tile per wave (rows mi*32.., cols wh*32..)
    f32x16 sacc;
    #pragma unroll
    for (int r = 0; r < 16; ++r) sacc[r] = 0.f;
    const int tl = wh * 32 + l32;
    #pragma unroll
    for (int kk = 0; kk < 16; ++kk) {
      int g = kk * 2 + half;                 // global 16B chunk of c
      short8 kf = *(const short8*)(sKV + tl * 256 + (g ^ (tl & 31)) * 8);
      sacc = __builtin_amdgcn_mfma_f32_32x32x16_bf16(qf[kk], kf, sacc, 0, 0, 0);
    }

    // sigmoid(x/16), mask t>=SL, write P (C-layout -> swizzled [s][t] rows)
    #pragma unroll
    for (int r = 0; r < 16; ++r) {
      int srow = mi * 32 + (r & 3) + 8 * (r >> 2) + 4 * half;
      float p = 1.f / (1.f + __expf(-sacc[r] * 0.0625f));
      sP[srow * 64 + (((tl >> 3) ^ (srow & 7)) << 3) + (tl & 7)] =
          (t0 + tl < SL) ? f2bf(p) : (unsigned short)0;
    }
    __syncthreads();   // sP ready AND all waves done reading K

    // stage V tile [256 d][64 t]: 8 chunks/row, slot s holds global chunk s^(d&7)
    #pragma unroll
    for (int i = 0; i < 8; ++i) {
      int u = i * 256 + tid;
      int drow = u >> 3, slot = u & 7;
      gld16(vtb + (size_t)drow * MP + n * 2048 + t0 + (slot ^ (drow & 7)) * 8,
            ((char*)sKV) + u * 16);
    }
    __syncthreads();

    // P·V: wave covers rows mi*32.., d-cols (wh*4+di)*32..
    #pragma unroll
    for (int kt = 0; kt < 4; ++kt) {
      int gc = kt * 2 + half;                // global 16B chunk of t
      int srow = mi * 32 + l32;
      short8 pa = *(const short8*)(sP + srow * 64 + ((gc ^ (srow & 7)) << 3));
      #pragma unroll
      for (int di = 0; di < 4; ++di) {
        int d = (wh * 4 + di) * 32 + l32;
        short8 vf = *(const short8*)(sKV + d * 64 + ((gc ^ (d & 7)) << 3));
        o[di] = __builtin_amdgcn_mfma_f32_32x32x16_bf16(pa, vf, o[di], 0, 0, 0);
      }
    }
  }

  // store: C layout col=d, row=s; each (n,d,s<SL) written exactly once
  #pragma unroll
  for (int di = 0; di < 4; ++di) {
    int d = (wh * 4 + di) * 32 + l32;
    float* op = out + (size_t)n * CO * SL + (size_t)d * SL;
    #pragma unroll
    for (int r = 0; r < 16; ++r) {
      int s = s0 + mi * 32 + (r & 3) + 8 * (r >> 2) + 4 * half;
      if (s < SL) op[s] = o[di][r];
    }
  }
}

extern "C" void kernel_launch(void* const* d_in, const int* in_sizes, int n_in,
                              void* d_out, int out_size, void* d_ws, size_t ws_size,
                              hipStream_t stream) {
  const float* x      = (const float*)d_in[0];
  const float* conv_w = (const float*)d_in[1];
  const float* conv_b = (const float*)d_in[2];
  const float* wq     = (const float*)d_in[3];
  const float* bq     = (const float*)d_in[4];
  const float* wk     = (const float*)d_in[5];
  const float* bk     = (const float*)d_in[6];
  const float* wv     = (const float*)d_in[7];
  const float* bv     = (const float*)d_in[8];

  char* ws = (char*)d_ws;
  unsigned short* xt  = (unsigned short*)(ws + XT_OFF);
  unsigned short* cw  = (unsigned short*)(ws + CW_OFF);
  unsigned short* wqb = (unsigned short*)(ws + WQ_OFF);
  unsigned short* wkb = (unsigned short*)(ws + WK_OFF);
  unsigned short* wvb = (unsigned short*)(ws + WV_OFF);
  unsigned short* hb  = (unsigned short*)(ws + H_OFF);
  unsigned short* qb  = (unsigned short*)(ws + Q_OFF);
  unsigned short* kb  = (unsigned short*)(ws + K_OFF);
  unsigned short* vtb = (unsigned short*)(ws + VT_OFF);

  hipLaunchKernelGGL(xpose_kernel, dim3(64, 4, 16), dim3(32, 8), 0, stream, x, xt);
  hipLaunchKernelGGL(wconv_kernel, dim3(1024), dim3(256), 0, stream, conv_w, cw);
  hipLaunchKernelGGL(wqkv_kernel,  dim3(192), dim3(256), 0, stream,
                     wq, wk, wv, wqb, wkb, wvb);
  hipLaunchKernelGGL(conv_gemm, dim3(16, 16, 2), dim3(256), 0, stream, xt, cw, conv_b, hb);
  hipLaunchKernelGGL(lin_gemm,  dim3(256, 2, 3), dim3(256), 0, stream,
                     hb, wqb, wkb, wvb, bq, bk, bv, qb, kb, vtb);
  hipLaunchKernelGGL(attn_kernel, dim3(32, 16), dim3(256), 0, stream,
                     qb, kb, vtb, (float*)d_out);
}